// Round 20
// baseline (289.977 us; speedup 1.0000x reference)
//
#include <hip/hip_runtime.h>
#include <hip/hip_fp16.h>

#define N_NODES 50000
#define N_EDGES 800000
#define NBKT 196            // ceil(50000 / 256) coarse buckets (dst >> 8)
#define EPB_BIN 4096        // edges per binning block
#define NB_BIN ((N_EDGES + EPB_BIN - 1) / EPB_BIN)   // 196

typedef _Float16 half8 __attribute__((ext_vector_type(8)));
typedef float f32x4 __attribute__((ext_vector_type(4)));

static __device__ __forceinline__ float lrelu(float x) { return fmaxf(x, 0.2f * x); }

// ---------------- CSR build: bucket counts ----------------
__global__ void __launch_bounds__(256) k_cntb(const int* __restrict__ dst,
                                              int* __restrict__ bcnt) {
    __shared__ int lcnt[NBKT];
    const int t = threadIdx.x;
    const int e0 = blockIdx.x * EPB_BIN;
    for (int i = t; i < NBKT; i += 256) lcnt[i] = 0;
    __syncthreads();
#pragma unroll
    for (int i = 0; i < 16; ++i) {
        const int e = e0 + i * 256 + t;
        if (e < N_EDGES) atomicAdd(&lcnt[dst[e] >> 8], 1);
    }
    __syncthreads();
    for (int i = t; i < NBKT; i += 256)
        if (lcnt[i]) atomicAdd(&bcnt[i], lcnt[i]);
}

// exclusive scan of bucket counts -> bktbase[0..NBKT]
__global__ void __launch_bounds__(256) k_scanb(const int* __restrict__ bcnt,
                                               int* __restrict__ bktbase,
                                               int* __restrict__ rowp) {
    __shared__ int sh[256];
    const int t = threadIdx.x;
    const int v = (t < NBKT) ? bcnt[t] : 0;
    sh[t] = v;
    __syncthreads();
    for (int off = 1; off < 256; off <<= 1) {
        const int u = (t >= off) ? sh[t - off] : 0;
        __syncthreads();
        sh[t] += u;
        __syncthreads();
    }
    if (t < NBKT) bktbase[t] = sh[t] - v;
    if (t == 0) { bktbase[NBKT] = N_EDGES; rowp[N_NODES] = N_EDGES; }
}

// bin edges into bucket-contiguous stage; entry = src(16b) | local(8b)<<16
__global__ void __launch_bounds__(256) k_bin(const int* __restrict__ src,
                                             const int* __restrict__ dst,
                                             const int* __restrict__ bktbase,
                                             int* __restrict__ bfill,
                                             unsigned int* __restrict__ stage) {
    __shared__ int lcnt[NBKT];
    __shared__ int gb[NBKT];
    __shared__ int lf[NBKT];
    const int t = threadIdx.x;
    const int e0 = blockIdx.x * EPB_BIN;
    for (int i = t; i < NBKT; i += 256) lcnt[i] = 0;
    __syncthreads();
    int dcache[16];
#pragma unroll
    for (int i = 0; i < 16; ++i) {
        const int e = e0 + i * 256 + t;
        if (e < N_EDGES) {
            const int d = dst[e];
            dcache[i] = d;
            atomicAdd(&lcnt[d >> 8], 1);
        } else dcache[i] = -1;
    }
    __syncthreads();
    for (int i = t; i < NBKT; i += 256) {
        gb[i] = bktbase[i] + atomicAdd(&bfill[i], lcnt[i]);
        lf[i] = 0;
    }
    __syncthreads();
#pragma unroll
    for (int i = 0; i < 16; ++i) {
        const int e = e0 + i * 256 + t;
        if (e < N_EDGES) {
            const int d = dcache[i];
            const int b = d >> 8;
            const int r = atomicAdd(&lf[b], 1);
            stage[gb[b] + r] = (unsigned int)src[e] | ((unsigned int)(d & 255) << 16);
        }
    }
}

// per bucket: count nodes, scan -> rowp, place col
__global__ void __launch_bounds__(256) k_bscatter2(const unsigned int* __restrict__ stage,
                                                   const int* __restrict__ bktbase,
                                                   int* __restrict__ rowp,
                                                   int* __restrict__ col) {
    __shared__ int lcnt[256];
    __shared__ int lpos[256];
    __shared__ int sexc[256];
    const int t = threadIdx.x;
    const int b = blockIdx.x;
    const int n0 = b << 8;
    const int base = bktbase[b], end = bktbase[b + 1];
    lcnt[t] = 0;
    __syncthreads();
    for (int j = base + t; j < end; j += 256)
        atomicAdd(&lcnt[(stage[j] >> 16) & 255], 1);
    __syncthreads();
    const int v = lcnt[t];
    lpos[t] = v;
    __syncthreads();
    for (int off = 1; off < 256; off <<= 1) {
        const int u = (t >= off) ? lpos[t - off] : 0;
        __syncthreads();
        lpos[t] += u;
        __syncthreads();
    }
    sexc[t] = lpos[t] - v;
    if (n0 + t < N_NODES) rowp[n0 + t] = base + sexc[t];
    lcnt[t] = 0;   // reuse as fill counters
    __syncthreads();
    for (int j = base + t; j < end; j += 256) {
        const unsigned int e = stage[j];
        const int local = (int)(e >> 16) & 255;
        const int r = atomicAdd(&lcnt[local], 1);
        col[base + sexc[local] + r] = (int)(e & 0xFFFFu);
    }
}

// ---------------- layer-1: packed xp[N][12] = {x[0..8], el1[0..2]}; er -------
__global__ void __launch_bounds__(256) k_el9p(const float* __restrict__ x,
                                              const float* __restrict__ W,
                                              const float* __restrict__ al,
                                              const float* __restrict__ ar,
                                              float* __restrict__ xp,
                                              float* __restrict__ er) {
    __shared__ float sWa[9 * 3];
    __shared__ float sWr[9 * 3];
    const int t = threadIdx.x;
    if (t < 27) {
        const int h = t / 9, k = t % 9;
        float sa = 0.f, sr = 0.f;
        for (int f = 0; f < 64; ++f) {
            const float w = W[k * 192 + h * 64 + f];
            sa += w * al[h * 64 + f];
            sr += w * ar[h * 64 + f];
        }
        sWa[k * 3 + h] = sa;
        sWr[k * 3 + h] = sr;
    }
    __syncthreads();
    const int n = blockIdx.x * 256 + t;
    if (n >= N_NODES) return;
    const float* __restrict__ xr = x + (size_t)n * 9;
    float xv[9];
    float a0 = 0.f, a1 = 0.f, a2 = 0.f, r0 = 0.f, r1 = 0.f, r2 = 0.f;
#pragma unroll
    for (int k = 0; k < 9; ++k) {
        xv[k] = xr[k];
        a0 += xv[k] * sWa[k * 3 + 0];
        a1 += xv[k] * sWa[k * 3 + 1];
        a2 += xv[k] * sWa[k * 3 + 2];
        r0 += xv[k] * sWr[k * 3 + 0];
        r1 += xv[k] * sWr[k * 3 + 1];
        r2 += xv[k] * sWr[k * 3 + 2];
    }
    float* __restrict__ xo = xp + (size_t)n * 12;
    *reinterpret_cast<float4*>(xo) = make_float4(xv[0], xv[1], xv[2], xv[3]);
    *reinterpret_cast<float4*>(xo + 4) = make_float4(xv[4], xv[5], xv[6], xv[7]);
    *reinterpret_cast<float4*>(xo + 8) = make_float4(xv[8], a0, a1, a2);
    *reinterpret_cast<float4*>(er + (size_t)n * 4) = make_float4(r0, r1, r2, 0.f);
}

// ---------------- L1 aggregation over packed xp (unchanged) ------------------
__global__ void __launch_bounds__(256) k_aggw9(const float* __restrict__ xp,
                                               const float* __restrict__ er,
                                               const int* __restrict__ rowp,
                                               const int* __restrict__ col,
                                               float* __restrict__ agg) {
    const int wv = threadIdx.x >> 6;
    const int lane = threadIdx.x & 63;
    const int n = blockIdx.x * 4 + wv;          // grid exact
    const int jb = rowp[n], je = rowp[n + 1];

    __shared__ float wbuf[4][3][68];
    __shared__ int cbuf[4][68];
    const float4 er4 = *reinterpret_cast<const float4*>(er + (size_t)n * 4);
    const int p = lane >> 5;
    const int l2 = lane & 31;
    const bool act = l2 < 27;
    const int h = act ? l2 / 9 : 0;
    const int k = act ? l2 % 9 : 0;
    float acc = 0.f;
    float sw0 = 0.f, sw1 = 0.f, sw2 = 0.f;

    for (int c0 = jb; c0 < je; c0 += 64) {
        const int cnt = min(64, je - c0);
        float w0 = 0.f, w1 = 0.f, w2 = 0.f;
        if (lane < cnt) {
            const int s = col[c0 + lane];
            cbuf[wv][lane] = s;
            const float4 e4 = *reinterpret_cast<const float4*>(xp + (size_t)s * 12 + 8);
            w0 = __expf(lrelu(e4.y + er4.x));
            w1 = __expf(lrelu(e4.z + er4.y));
            w2 = __expf(lrelu(e4.w + er4.z));
            wbuf[wv][0][lane] = w0;
            wbuf[wv][1][lane] = w1;
            wbuf[wv][2][lane] = w2;
        }
        sw0 += w0; sw1 += w1; sw2 += w2;
        int e = 0;
        for (; e + 4 <= cnt; e += 4) {
            const int s0 = cbuf[wv][e + p];
            const int s1 = cbuf[wv][e + 2 + p];
            const float we0 = wbuf[wv][h][e + p];
            const float we1 = wbuf[wv][h][e + 2 + p];
            const float x0 = xp[(size_t)s0 * 12 + k];
            const float x1 = xp[(size_t)s1 * 12 + k];
            if (act) acc += we0 * x0 + we1 * x1;
        }
        for (; e + 2 <= cnt; e += 2) {
            const int s0 = cbuf[wv][e + p];
            const float we0 = wbuf[wv][h][e + p];
            const float x0 = xp[(size_t)s0 * 12 + k];
            if (act) acc += we0 * x0;
        }
        if (e < cnt && p == 0 && act) {
            const int s0 = cbuf[wv][e];
            acc += wbuf[wv][h][e] * xp[(size_t)s0 * 12 + k];
        }
    }
    acc += __shfl_xor(acc, 32);
#pragma unroll
    for (int off = 32; off > 0; off >>= 1) {
        sw0 += __shfl_xor(sw0, off);
        sw1 += __shfl_xor(sw1, off);
        sw2 += __shfl_xor(sw2, off);
    }
    if (lane < 27) {
        const float swh = (h == 0) ? sw0 : (h == 1 ? sw1 : sw2);
        agg[(size_t)n * 28 + lane] = (je > jb) ? acc / swh : 0.f;
    }
    if (lane == 27) agg[(size_t)n * 28 + 27] = 0.f;
}

// ---------------- L2 aggregation v2: 16B/lane, 8 edges per instruction -------
// lane: fb=(lane&7)*8 (feature block), ep=lane>>3 (edge phase). One dwordx4
// gather covers 8 fp16 features; 64 lanes = 8 edges x 128B row. 8 addr/edge.
__global__ void __launch_bounds__(256) k_aggw64(const __half* __restrict__ x,
                                                const float* __restrict__ el,
                                                const float* __restrict__ er,
                                                const int* __restrict__ rowp,
                                                const int* __restrict__ col,
                                                __half* __restrict__ agg) {
    const int wv = threadIdx.x >> 6;
    const int lane = threadIdx.x & 63;
    const int n = blockIdx.x * 4 + wv;          // grid exact: 12500*4
    const int jb = rowp[n], je = rowp[n + 1];

    __shared__ float wbuf[4][3][68];
    __shared__ int cbuf[4][68];
    const float4 er4 = *reinterpret_cast<const float4*>(er + (size_t)n * 4);
    const int fb = (lane & 7) * 8;
    const int ep = lane >> 3;
    float acc[8][3];
#pragma unroll
    for (int f = 0; f < 8; ++f) { acc[f][0] = 0.f; acc[f][1] = 0.f; acc[f][2] = 0.f; }
    float sw0 = 0.f, sw1 = 0.f, sw2 = 0.f;

    for (int c0 = jb; c0 < je; c0 += 64) {
        const int cnt = min(64, je - c0);
        float w0 = 0.f, w1 = 0.f, w2 = 0.f;
        if (lane < cnt) {
            const int s = col[c0 + lane];
            cbuf[wv][lane] = s;
            const float4 e4 = *reinterpret_cast<const float4*>(el + (size_t)s * 4);
            w0 = __expf(lrelu(e4.x + er4.x));
            w1 = __expf(lrelu(e4.y + er4.y));
            w2 = __expf(lrelu(e4.z + er4.z));
            wbuf[wv][0][lane] = w0;
            wbuf[wv][1][lane] = w1;
            wbuf[wv][2][lane] = w2;
        }
        sw0 += w0; sw1 += w1; sw2 += w2;
        for (int e = ep; e < cnt; e += 8) {
            const int s = cbuf[wv][e];
            const half8 xv = *reinterpret_cast<const half8*>(x + (size_t)s * 64 + fb);
            const float we0 = wbuf[wv][0][e];
            const float we1 = wbuf[wv][1][e];
            const float we2 = wbuf[wv][2][e];
#pragma unroll
            for (int f = 0; f < 8; ++f) {
                const float xf = (float)xv[f];
                acc[f][0] += we0 * xf;
                acc[f][1] += we1 * xf;
                acc[f][2] += we2 * xf;
            }
        }
    }
    // combine edge phases (lanes sharing fb differ in bits 3..5)
#pragma unroll
    for (int f = 0; f < 8; ++f)
#pragma unroll
        for (int h = 0; h < 3; ++h) {
            acc[f][h] += __shfl_xor(acc[f][h], 8);
            acc[f][h] += __shfl_xor(acc[f][h], 16);
            acc[f][h] += __shfl_xor(acc[f][h], 32);
        }
#pragma unroll
    for (int off = 32; off > 0; off >>= 1) {
        sw0 += __shfl_xor(sw0, off);
        sw1 += __shfl_xor(sw1, off);
        sw2 += __shfl_xor(sw2, off);
    }
    if (ep == 0) {   // lanes 0..7, fb = lane*8
        __half* __restrict__ ao = agg + (size_t)n * 192;
        half8 o0, o1, o2;
        if (je > jb) {
            const float i0 = 1.f / sw0, i1 = 1.f / sw1, i2 = 1.f / sw2;
#pragma unroll
            for (int f = 0; f < 8; ++f) {
                o0[f] = (_Float16)(acc[f][0] * i0);
                o1[f] = (_Float16)(acc[f][1] * i1);
                o2[f] = (_Float16)(acc[f][2] * i2);
            }
        } else {
#pragma unroll
            for (int f = 0; f < 8; ++f) { o0[f] = (_Float16)0.f; o1[f] = (_Float16)0.f; o2[f] = (_Float16)0.f; }
        }
        *reinterpret_cast<half8*>(ao + fb) = o0;
        *reinterpret_cast<half8*>(ao + 64 + fb) = o1;
        *reinterpret_cast<half8*>(ao + 128 + fb) = o2;
    }
}

// ---------------- Wa2/Wr2 precompute (float4-packed [64][4]) -----------------
__global__ void __launch_bounds__(192) k_prepA(const float* __restrict__ W2,
                                               const float* __restrict__ al2,
                                               const float* __restrict__ ar2,
                                               float* __restrict__ Wa2,
                                               float* __restrict__ Wr2) {
    const int t = threadIdx.x;
    const int h = t >> 6, k = t & 63;
    float sa = 0.f, sr = 0.f;
    for (int f = 0; f < 64; ++f) {
        const float w = W2[k * 192 + h * 64 + f];
        sa += w * al2[h * 64 + f];
        sr += w * ar2[h * 64 + f];
    }
    Wa2[k * 4 + h] = sa;
    Wr2[k * 4 + h] = sr;
    if (h == 0) { Wa2[k * 4 + 3] = 0.f; Wr2[k * 4 + 3] = 0.f; }
}

// ---------------- layer-1 post-agg GEMM + fused el2/er2 ----------------------
template <int KE, int AS, int HOFF>
__global__ void __launch_bounds__(192) k_gemm2(const float* __restrict__ agg,
                                               const float* __restrict__ W,
                                               const float* __restrict__ bias,
                                               const float* __restrict__ Wa2,
                                               const float* __restrict__ Wr2,
                                               __half* __restrict__ hout,
                                               float* __restrict__ el,
                                               float* __restrict__ er) {
    const int NPB = 16;
    const int h = threadIdx.x >> 6;
    const int c = threadIdx.x & 63;
    float wreg[KE];
#pragma unroll
    for (int k = 0; k < KE; ++k) wreg[k] = W[k * 192 + h * 64 + c];

    __shared__ float At[NPB * AS];
    __shared__ float part[3][NPB][64];
    const int nbase = blockIdx.x * NPB;         // 3125 * 16 = 50000 exact

    const float4* __restrict__ src4 =
        reinterpret_cast<const float4*>(agg + (size_t)nbase * AS);
    float4* At4 = reinterpret_cast<float4*>(At);
    for (int idx = threadIdx.x; idx < NPB * AS / 4; idx += 192) At4[idx] = src4[idx];
    __syncthreads();

#pragma unroll
    for (int i = 0; i < NPB; ++i) {
        const float* __restrict__ ar = At + i * AS + h * HOFF;
        float acc = 0.f;
#pragma unroll
        for (int k = 0; k < KE; ++k) acc += ar[k] * wreg[k];
        part[h][i][c] = acc;
    }
    __syncthreads();
    const int lane = threadIdx.x & 63;
    const float4 wa = *reinterpret_cast<const float4*>(Wa2 + lane * 4);
    const float4 wr = *reinterpret_cast<const float4*>(Wr2 + lane * 4);
    for (int idx = threadIdx.x; idx < NPB * 64; idx += 192) {
        const int i = idx >> 6, cc = idx & 63;  // cc == lane (192 % 64 == 0)
        const float v = part[0][i][cc] + part[1][i][cc] + part[2][i][cc]
                      + bias[cc] + bias[64 + cc] + bias[128 + cc];
        hout[(size_t)(nbase + i) * 64 + cc] = __float2half(v);
        float e0 = v * wa.x, e1 = v * wa.y, e2 = v * wa.z;
        float r0 = v * wr.x, r1 = v * wr.y, r2 = v * wr.z;
#pragma unroll
        for (int off = 32; off > 0; off >>= 1) {
            e0 += __shfl_xor(e0, off); e1 += __shfl_xor(e1, off); e2 += __shfl_xor(e2, off);
            r0 += __shfl_xor(r0, off); r1 += __shfl_xor(r1, off); r2 += __shfl_xor(r2, off);
        }
        if (lane == 0) {
            *reinterpret_cast<float4*>(el + (size_t)(nbase + i) * 4) = make_float4(e0, e1, e2, 0.f);
            *reinterpret_cast<float4*>(er + (size_t)(nbase + i) * 4) = make_float4(r0, r1, r2, 0.f);
        }
    }
}

// ---------------- W2 -> fp16 effective-transpose table Wt16[n][192] ----------
__global__ void __launch_bounds__(256) k_prepW(const float* __restrict__ W,
                                               __half* __restrict__ Wt16) {
    const int idx = blockIdx.x * 256 + threadIdx.x;
    if (idx >= 64 * 192) return;
    const int n = idx / 192, ke = idx % 192;
    Wt16[idx] = __float2half(W[(ke & 63) * 192 + (ke >> 6) * 64 + n]);
}

// ---------------- layer-2 GEMM via MFMA, fragment-direct ---------------------
__global__ void __launch_bounds__(256) k_gemm3m(const __half* __restrict__ agg,
                                                const __half* __restrict__ Wt,
                                                const float* __restrict__ bias,
                                                __half* __restrict__ hout) {
    const int wv = threadIdx.x >> 6;
    const int lane = threadIdx.x & 63;
    const int quad = lane >> 4;
    const int t16 = lane & 15;
    const int nwave = blockIdx.x * 64 + wv * 16;

    const int arow = min(nwave + t16, N_NODES - 1);
    half8 a[6];
#pragma unroll
    for (int kb = 0; kb < 6; ++kb)
        a[kb] = *reinterpret_cast<const half8*>(agg + (size_t)arow * 192 + kb * 32 + quad * 8);

    float bs[4];
#pragma unroll
    for (int nt = 0; nt < 4; ++nt) {
        const int c = nt * 16 + t16;
        bs[nt] = bias[c] + bias[64 + c] + bias[128 + c];
    }

#pragma unroll
    for (int nt = 0; nt < 4; ++nt) {
        const __half* __restrict__ bt = Wt + (size_t)(nt * 16 + t16) * 192 + quad * 8;
        f32x4 acc = {0.f, 0.f, 0.f, 0.f};
#pragma unroll
        for (int kb = 0; kb < 6; ++kb) {
            const half8 b = *reinterpret_cast<const half8*>(bt + kb * 32);
            acc = __builtin_amdgcn_mfma_f32_16x16x32_f16(a[kb], b, acc, 0, 0, 0);
        }
        const int c = nt * 16 + t16;
#pragma unroll
        for (int r = 0; r < 4; ++r) {
            const int node = nwave + quad * 4 + r;
            if (node < N_NODES)
                hout[(size_t)node * 64 + c] = __float2half(acc[r] + bs[nt]);
        }
    }
}

// ---------------- layer 3: packed feat3p[N][12]={el3[0..2],feat[0..5],pad} ---
__global__ void __launch_bounds__(256) k_feat3(const __half* __restrict__ x,
                                               const float* __restrict__ W3,
                                               const float* __restrict__ al3,
                                               const float* __restrict__ ar3,
                                               float* __restrict__ feat3p,
                                               float* __restrict__ er3) {
    __shared__ float Wl[64 * 6];
    __shared__ float Wal[64 * 3];
    __shared__ float Wrl[64 * 3];
    __shared__ float xl[32 * 68];
    const int t = threadIdx.x;
    const int n0 = blockIdx.x * 32;
    const int nvalid = min(32, N_NODES - n0);
    for (int idx = t; idx < 384; idx += 256) Wl[idx] = W3[idx];
    if (t < 192) {
        const int k = t & 63, h = t >> 6;
        Wal[k * 3 + h] = W3[k * 6 + h * 2] * al3[h * 2] + W3[k * 6 + h * 2 + 1] * al3[h * 2 + 1];
        Wrl[k * 3 + h] = W3[k * 6 + h * 2] * ar3[h * 2] + W3[k * 6 + h * 2 + 1] * ar3[h * 2 + 1];
    }
    for (int idx = t; idx < nvalid * 64; idx += 256)
        xl[(idx >> 6) * 68 + (idx & 63)] = __half2float(x[(size_t)n0 * 64 + idx]);
    __syncthreads();

    const int i = t >> 3;
    const int slot = t & 7;
    if (i < nvalid && slot < 6) {
        float acc = 0.f;
#pragma unroll
        for (int k4 = 0; k4 < 16; ++k4) {
            const float4 xv = *reinterpret_cast<const float4*>(&xl[i * 68 + 4 * k4]);
            acc += Wl[(4 * k4 + 0) * 6 + slot] * xv.x;
            acc += Wl[(4 * k4 + 1) * 6 + slot] * xv.y;
            acc += Wl[(4 * k4 + 2) * 6 + slot] * xv.z;
            acc += Wl[(4 * k4 + 3) * 6 + slot] * xv.w;
        }
        feat3p[(size_t)(n0 + i) * 12 + 3 + slot] = acc;   // feat at offsets 3..8
    }
    if (t < 192) {
        const int ii = t / 6, ss = t % 6;
        if (ii < nvalid) {
            const int hh = (ss < 3) ? ss : ss - 3;
            const float* __restrict__ wt = (ss < 3) ? Wal : Wrl;
            float acc = 0.f;
#pragma unroll 4
            for (int k = 0; k < 64; ++k) acc += xl[ii * 68 + k] * wt[k * 3 + hh];
            if (ss < 3) feat3p[(size_t)(n0 + ii) * 12 + hh] = acc;   // el3 at 0..2
            else        er3[(size_t)(n0 + ii) * 4 + hh] = acc;
        }
    }
}

// ---------------- layer-3 aggregation v2: wave/node, 8 edges/instruction -----
// lane: s8=lane&7 (slot; 0..5 used), ep=lane>>3. Per edge: 1 col + 1 float4
// (phase1) + 8 x 4B row loads (phase2) = ~10 addresses.
__global__ void __launch_bounds__(256) k_agg3(const float* __restrict__ feat3p,
                                              const float* __restrict__ er3,
                                              const float* __restrict__ b3,
                                              const int* __restrict__ rowp,
                                              const int* __restrict__ col,
                                              float* __restrict__ out) {
    const int wv = threadIdx.x >> 6;
    const int lane = threadIdx.x & 63;
    const int n = blockIdx.x * 4 + wv;          // grid exact: 12500*4
    const int jb = rowp[n], je = rowp[n + 1];

    __shared__ float wbuf[4][3][68];
    __shared__ int cbuf[4][68];
    __shared__ float comb[4][8];
    const float4 er4 = *reinterpret_cast<const float4*>(er3 + (size_t)n * 4);
    const int s8 = lane & 7;
    const int ep = lane >> 3;
    const int hh = (s8 < 6) ? (s8 >> 1) : 0;
    float acc = 0.f;
    float sw0 = 0.f, sw1 = 0.f, sw2 = 0.f;

    for (int c0 = jb; c0 < je; c0 += 64) {
        const int cnt = min(64, je - c0);
        float w0 = 0.f, w1 = 0.f, w2 = 0.f;
        if (lane < cnt) {
            const int s = col[c0 + lane];
            cbuf[wv][lane] = s;
            // packed row head: {el0, el1, el2, feat0}
            const float4 e4 = *reinterpret_cast<const float4*>(feat3p + (size_t)s * 12);
            w0 = __expf(lrelu(e4.x + er4.x));
            w1 = __expf(lrelu(e4.y + er4.y));
            w2 = __expf(lrelu(e4.z + er4.z));
            wbuf[wv][0][lane] = w0;
            wbuf[wv][1][lane] = w1;
            wbuf[wv][2][lane] = w2;
        }
        sw0 += w0; sw1 += w1; sw2 += w2;
        for (int e = ep; e < cnt; e += 8) {
            const int s = cbuf[wv][e];
            const float w = wbuf[wv][hh][e];
            const float f = feat3p[(size_t)s * 12 + 3 + s8];  // s8=6,7 read pad
            acc += w * f;
        }
    }
    acc += __shfl_xor(acc, 8);
    acc += __shfl_xor(acc, 16);
    acc += __shfl_xor(acc, 32);
#pragma unroll
    for (int off = 32; off > 0; off >>= 1) {
        sw0 += __shfl_xor(sw0, off);
        sw1 += __shfl_xor(sw1, off);
        sw2 += __shfl_xor(sw2, off);
    }
    if (ep == 0 && s8 < 6) {
        const float swh = (hh == 0) ? sw0 : (hh == 1 ? sw1 : sw2);
        comb[wv][s8] = (je > jb) ? acc / swh : 0.f;
    }
    // same-wave LDS producer/consumer: in-order
    if (lane < 2) {
        const float bc = b3[lane] + b3[lane + 2] + b3[lane + 4];
        out[(size_t)n * 2 + lane] = comb[wv][lane] + comb[wv][lane + 2] + comb[wv][lane + 4] + bc;
    }
}

extern "C" void kernel_launch(void* const* d_in, const int* in_sizes, int n_in,
                              void* d_out, int out_size, void* d_ws, size_t ws_size,
                              hipStream_t stream) {
    const float* feats = (const float*)d_in[0];
    const int* src = (const int*)d_in[1];
    const int* dst = (const int*)d_in[2];
    const float* W1 = (const float*)d_in[3];
    const float* al1 = (const float*)d_in[4];
    const float* ar1 = (const float*)d_in[5];
    const float* b1 = (const float*)d_in[6];
    const float* W2 = (const float*)d_in[7];
    const float* al2 = (const float*)d_in[8];
    const float* ar2 = (const float*)d_in[9];
    const float* b2 = (const float*)d_in[10];
    const float* W3 = (const float*)d_in[11];
    const float* al3 = (const float*)d_in[12];
    const float* ar3 = (const float*)d_in[13];
    const float* b3 = (const float*)d_in[14];
    float* out = (float*)d_out;

    char* ws = (char*)d_ws;
    size_t off = 0;
    auto alloc = [&](size_t bytes) {
        void* p = ws + off;
        off += (bytes + 255) & ~(size_t)255;
        return p;
    };
    float* agg = (float*)alloc((size_t)N_NODES * 28 * 4);        // L1 agg fp32 [N][28]
    __half* aggH = (__half*)alloc((size_t)N_NODES * 192 * 2);    // L2 agg fp16 [N][192]
    __half* hbufH = (__half*)alloc((size_t)N_NODES * 64 * 2);    // fp16 hidden
    float* xp = (float*)alloc((size_t)N_NODES * 12 * 4);         // packed x+el1
    float* el = (float*)alloc((size_t)N_NODES * 4 * 4);
    float* er = (float*)alloc((size_t)N_NODES * 4 * 4);
    int* bcnt = (int*)alloc(512 * 4);                            // bcnt[256] + bfill[256]
    int* bfill = bcnt + 256;
    int* bktbase = (int*)alloc(256 * 4);
    int* rowp = (int*)alloc((size_t)(N_NODES + 1) * 4);
    int* col = (int*)alloc((size_t)N_EDGES * 4);
    unsigned int* stage = (unsigned int*)alloc((size_t)N_EDGES * 4);
    __half* Wt16 = (__half*)alloc((size_t)64 * 192 * 2);         // 24 KB fp16 W2^T
    float* Wa2 = (float*)alloc(256 * 4);
    float* Wr2 = (float*)alloc(256 * 4);
    float* feat3p = (float*)alloc((size_t)N_NODES * 12 * 4);     // packed el3+feat3
    (void)ws_size;

    // ---- CSR build ----
    hipMemsetAsync(bcnt, 0, 512 * 4, stream);
    k_cntb<<<NB_BIN, 256, 0, stream>>>(dst, bcnt);
    k_scanb<<<1, 256, 0, stream>>>(bcnt, bktbase, rowp);
    k_bin<<<NB_BIN, 256, 0, stream>>>(src, dst, bktbase, bfill, stage);
    k_bscatter2<<<NBKT, 256, 0, stream>>>(stage, bktbase, rowp, col);
    k_prepW<<<48, 256, 0, stream>>>(W2, Wt16);
    k_prepA<<<1, 192, 0, stream>>>(W2, al2, ar2, Wa2, Wr2);

    const int ab = N_NODES / 4;             // wave/node kernels: 4 waves/block
    const int gb2 = N_NODES / 16;           // k_gemm2: 16 nodes/block
    const int gbm = (N_NODES + 63) / 64;    // k_gemm3m: 64 nodes/block
    const int nb = (N_NODES + 255) / 256;
    const int nb3 = (N_NODES + 31) / 32;

    // ---- layer 1 (packed xp) ----
    k_el9p<<<nb, 256, 0, stream>>>(feats, W1, al1, ar1, xp, er);
    k_aggw9<<<ab, 256, 0, stream>>>(xp, er, rowp, col, agg);
    k_gemm2<9, 28, 9><<<gb2, 192, 0, stream>>>(agg, W1, b1, Wa2, Wr2, hbufH, el, er);

    // ---- layer 2 (el2/er2 from k_gemm2 epilogue) ----
    k_aggw64<<<ab, 256, 0, stream>>>(hbufH, el, er, rowp, col, aggH);
    k_gemm3m<<<gbm, 256, 0, stream>>>(aggH, Wt16, b2, hbufH);

    // ---- layer 3 (packed feat3p; er3 in er buffer) ----
    k_feat3<<<nb3, 256, 0, stream>>>(hbufH, W3, al3, ar3, feat3p, er);
    k_agg3<<<ab, 256, 0, stream>>>(feat3p, er, b3, rowp, col, out);
}

// Round 21
// 269.475 us; speedup vs baseline: 1.0761x; 1.0761x over previous
//
#include <hip/hip_runtime.h>
#include <hip/hip_fp16.h>

#define N_NODES 50000
#define N_EDGES 800000
#define NBKT 196            // ceil(50000 / 256) coarse buckets (dst >> 8)
#define EPB_BIN 4096        // edges per binning block
#define NB_BIN ((N_EDGES + EPB_BIN - 1) / EPB_BIN)   // 196

typedef _Float16 half8 __attribute__((ext_vector_type(8)));
typedef float f32x4 __attribute__((ext_vector_type(4)));

static __device__ __forceinline__ float lrelu(float x) { return fmaxf(x, 0.2f * x); }

// ---------------- CSR build: bucket counts ----------------
__global__ void __launch_bounds__(256) k_cntb(const int* __restrict__ dst,
                                              int* __restrict__ bcnt) {
    __shared__ int lcnt[NBKT];
    const int t = threadIdx.x;
    const int e0 = blockIdx.x * EPB_BIN;
    for (int i = t; i < NBKT; i += 256) lcnt[i] = 0;
    __syncthreads();
#pragma unroll
    for (int i = 0; i < 16; ++i) {
        const int e = e0 + i * 256 + t;
        if (e < N_EDGES) atomicAdd(&lcnt[dst[e] >> 8], 1);
    }
    __syncthreads();
    for (int i = t; i < NBKT; i += 256)
        if (lcnt[i]) atomicAdd(&bcnt[i], lcnt[i]);
}

// exclusive scan of bucket counts -> bktbase[0..NBKT]
__global__ void __launch_bounds__(256) k_scanb(const int* __restrict__ bcnt,
                                               int* __restrict__ bktbase,
                                               int* __restrict__ rowp) {
    __shared__ int sh[256];
    const int t = threadIdx.x;
    const int v = (t < NBKT) ? bcnt[t] : 0;
    sh[t] = v;
    __syncthreads();
    for (int off = 1; off < 256; off <<= 1) {
        const int u = (t >= off) ? sh[t - off] : 0;
        __syncthreads();
        sh[t] += u;
        __syncthreads();
    }
    if (t < NBKT) bktbase[t] = sh[t] - v;
    if (t == 0) { bktbase[NBKT] = N_EDGES; rowp[N_NODES] = N_EDGES; }
}

// bin edges into bucket-contiguous stage; entry = src(16b) | local(8b)<<16
__global__ void __launch_bounds__(256) k_bin(const int* __restrict__ src,
                                             const int* __restrict__ dst,
                                             const int* __restrict__ bktbase,
                                             int* __restrict__ bfill,
                                             unsigned int* __restrict__ stage) {
    __shared__ int lcnt[NBKT];
    __shared__ int gb[NBKT];
    __shared__ int lf[NBKT];
    const int t = threadIdx.x;
    const int e0 = blockIdx.x * EPB_BIN;
    for (int i = t; i < NBKT; i += 256) lcnt[i] = 0;
    __syncthreads();
    int dcache[16];
#pragma unroll
    for (int i = 0; i < 16; ++i) {
        const int e = e0 + i * 256 + t;
        if (e < N_EDGES) {
            const int d = dst[e];
            dcache[i] = d;
            atomicAdd(&lcnt[d >> 8], 1);
        } else dcache[i] = -1;
    }
    __syncthreads();
    for (int i = t; i < NBKT; i += 256) {
        gb[i] = bktbase[i] + atomicAdd(&bfill[i], lcnt[i]);
        lf[i] = 0;
    }
    __syncthreads();
#pragma unroll
    for (int i = 0; i < 16; ++i) {
        const int e = e0 + i * 256 + t;
        if (e < N_EDGES) {
            const int d = dcache[i];
            const int b = d >> 8;
            const int r = atomicAdd(&lf[b], 1);
            stage[gb[b] + r] = (unsigned int)src[e] | ((unsigned int)(d & 255) << 16);
        }
    }
}

// per bucket: count nodes, scan -> rowp, place col
__global__ void __launch_bounds__(256) k_bscatter2(const unsigned int* __restrict__ stage,
                                                   const int* __restrict__ bktbase,
                                                   int* __restrict__ rowp,
                                                   int* __restrict__ col) {
    __shared__ int lcnt[256];
    __shared__ int lpos[256];
    __shared__ int sexc[256];
    const int t = threadIdx.x;
    const int b = blockIdx.x;
    const int n0 = b << 8;
    const int base = bktbase[b], end = bktbase[b + 1];
    lcnt[t] = 0;
    __syncthreads();
    for (int j = base + t; j < end; j += 256)
        atomicAdd(&lcnt[(stage[j] >> 16) & 255], 1);
    __syncthreads();
    const int v = lcnt[t];
    lpos[t] = v;
    __syncthreads();
    for (int off = 1; off < 256; off <<= 1) {
        const int u = (t >= off) ? lpos[t - off] : 0;
        __syncthreads();
        lpos[t] += u;
        __syncthreads();
    }
    sexc[t] = lpos[t] - v;
    if (n0 + t < N_NODES) rowp[n0 + t] = base + sexc[t];
    lcnt[t] = 0;   // reuse as fill counters
    __syncthreads();
    for (int j = base + t; j < end; j += 256) {
        const unsigned int e = stage[j];
        const int local = (int)(e >> 16) & 255;
        const int r = atomicAdd(&lcnt[local], 1);
        col[base + sexc[local] + r] = (int)(e & 0xFFFFu);
    }
}

// ---------------- layer-1: packed xp[N][12] = {x[0..8], el1[0..2]}; er -------
__global__ void __launch_bounds__(256) k_el9p(const float* __restrict__ x,
                                              const float* __restrict__ W,
                                              const float* __restrict__ al,
                                              const float* __restrict__ ar,
                                              float* __restrict__ xp,
                                              float* __restrict__ er) {
    __shared__ float sWa[9 * 3];
    __shared__ float sWr[9 * 3];
    const int t = threadIdx.x;
    if (t < 27) {
        const int h = t / 9, k = t % 9;
        float sa = 0.f, sr = 0.f;
        for (int f = 0; f < 64; ++f) {
            const float w = W[k * 192 + h * 64 + f];
            sa += w * al[h * 64 + f];
            sr += w * ar[h * 64 + f];
        }
        sWa[k * 3 + h] = sa;
        sWr[k * 3 + h] = sr;
    }
    __syncthreads();
    const int n = blockIdx.x * 256 + t;
    if (n >= N_NODES) return;
    const float* __restrict__ xr = x + (size_t)n * 9;
    float xv[9];
    float a0 = 0.f, a1 = 0.f, a2 = 0.f, r0 = 0.f, r1 = 0.f, r2 = 0.f;
#pragma unroll
    for (int k = 0; k < 9; ++k) {
        xv[k] = xr[k];
        a0 += xv[k] * sWa[k * 3 + 0];
        a1 += xv[k] * sWa[k * 3 + 1];
        a2 += xv[k] * sWa[k * 3 + 2];
        r0 += xv[k] * sWr[k * 3 + 0];
        r1 += xv[k] * sWr[k * 3 + 1];
        r2 += xv[k] * sWr[k * 3 + 2];
    }
    float* __restrict__ xo = xp + (size_t)n * 12;
    *reinterpret_cast<float4*>(xo) = make_float4(xv[0], xv[1], xv[2], xv[3]);
    *reinterpret_cast<float4*>(xo + 4) = make_float4(xv[4], xv[5], xv[6], xv[7]);
    *reinterpret_cast<float4*>(xo + 8) = make_float4(xv[8], a0, a1, a2);
    *reinterpret_cast<float4*>(er + (size_t)n * 4) = make_float4(r0, r1, r2, 0.f);
}

// ---------------- L1 aggregation: lane-per-edge, quarter-wave per node -------
// 16 lanes per node; each lane owns one edge: 3 dwordx4 = full packed row
// (x[0..8] + el[0..2]) -> 13 dwords/edge total (incl. col), no head duplication.
// Butterfly over the 4 quarter-lanes offsets serves 4 nodes per wave at once.
__global__ void __launch_bounds__(256) k_aggw9(const float* __restrict__ xp,
                                               const float* __restrict__ er,
                                               const int* __restrict__ rowp,
                                               const int* __restrict__ col,
                                               float* __restrict__ agg) {
    const int tid = threadIdx.x;
    const int wv = tid >> 6;
    const int lane = tid & 63;
    const int q = lane >> 4;            // node slot within wave
    const int ql = lane & 15;           // lane within quarter
    const int n = (blockIdx.x * 4 + wv) * 4 + q;   // grid exact: 3125*4*4 = 50000
    const int jb = rowp[n], je = rowp[n + 1];
    const float4 er4 = *reinterpret_cast<const float4*>(er + (size_t)n * 4);

    float acc[27];
#pragma unroll
    for (int j = 0; j < 27; ++j) acc[j] = 0.f;
    float sw0 = 0.f, sw1 = 0.f, sw2 = 0.f;

    for (int e = jb + ql; e < je; e += 16) {
        const int s = col[e];
        const float* __restrict__ row = xp + (size_t)s * 12;
        const float4 xa = *reinterpret_cast<const float4*>(row);
        const float4 xb = *reinterpret_cast<const float4*>(row + 4);
        const float4 xc = *reinterpret_cast<const float4*>(row + 8);
        const float w0 = __expf(lrelu(xc.y + er4.x));
        const float w1 = __expf(lrelu(xc.z + er4.y));
        const float w2 = __expf(lrelu(xc.w + er4.z));
        sw0 += w0; sw1 += w1; sw2 += w2;
        const float xv[9] = {xa.x, xa.y, xa.z, xa.w, xb.x, xb.y, xb.z, xb.w, xc.x};
#pragma unroll
        for (int k = 0; k < 9; ++k) {
            acc[0 + k]  += w0 * xv[k];
            acc[9 + k]  += w1 * xv[k];
            acc[18 + k] += w2 * xv[k];
        }
    }
    // reduce within each quarter (handles all 4 nodes of the wave at once)
#pragma unroll
    for (int off = 1; off < 16; off <<= 1) {
        sw0 += __shfl_xor(sw0, off);
        sw1 += __shfl_xor(sw1, off);
        sw2 += __shfl_xor(sw2, off);
#pragma unroll
        for (int j = 0; j < 27; ++j) acc[j] += __shfl_xor(acc[j], off);
    }
    if (ql == 0) {
        const bool has = (je > jb);
        const float i0 = has ? 1.f / sw0 : 0.f;
        const float i1 = has ? 1.f / sw1 : 0.f;
        const float i2 = has ? 1.f / sw2 : 0.f;
        float o[28];
#pragma unroll
        for (int k = 0; k < 9; ++k) {
            o[k] = acc[k] * i0;
            o[9 + k] = acc[9 + k] * i1;
            o[18 + k] = acc[18 + k] * i2;
        }
        o[27] = 0.f;
        float4* __restrict__ ao = reinterpret_cast<float4*>(agg + (size_t)n * 28);
#pragma unroll
        for (int v = 0; v < 7; ++v)
            ao[v] = make_float4(o[4 * v], o[4 * v + 1], o[4 * v + 2], o[4 * v + 3]);
    }
}

// ---------------- L2 aggregation v1 (reverted): 2 edges/gather, 4B/lane ------
// At the TA floor: 32 addr-dwords/edge for a 128B row (measured 41.5us).
__global__ void __launch_bounds__(256) k_aggw64(const __half* __restrict__ x,
                                                const float* __restrict__ el,
                                                const float* __restrict__ er,
                                                const int* __restrict__ rowp,
                                                const int* __restrict__ col,
                                                __half* __restrict__ agg) {
    const int wv = threadIdx.x >> 6;
    const int lane = threadIdx.x & 63;
    const int n = blockIdx.x * 4 + wv;          // grid exact
    const int jb = rowp[n], je = rowp[n + 1];

    __shared__ float wbuf[4][3][68];
    __shared__ int cbuf[4][68];
    const float4 er4 = *reinterpret_cast<const float4*>(er + (size_t)n * 4);
    const int p = lane >> 5;
    const int f0 = (lane & 31) * 2;
    float a00 = 0.f, a01 = 0.f, a02 = 0.f;
    float a10 = 0.f, a11 = 0.f, a12 = 0.f;
    float sw0 = 0.f, sw1 = 0.f, sw2 = 0.f;

    for (int c0 = jb; c0 < je; c0 += 64) {
        const int cnt = min(64, je - c0);
        float w0 = 0.f, w1 = 0.f, w2 = 0.f;
        if (lane < cnt) {
            const int s = col[c0 + lane];
            cbuf[wv][lane] = s;
            const float4 e4 = *reinterpret_cast<const float4*>(el + (size_t)s * 4);
            w0 = __expf(lrelu(e4.x + er4.x));
            w1 = __expf(lrelu(e4.y + er4.y));
            w2 = __expf(lrelu(e4.z + er4.z));
            wbuf[wv][0][lane] = w0;
            wbuf[wv][1][lane] = w1;
            wbuf[wv][2][lane] = w2;
        }
        sw0 += w0; sw1 += w1; sw2 += w2;
        int e = 0;
        for (; e + 2 <= cnt; e += 2) {
            const int ei = e + p;
            const int s = cbuf[wv][ei];
            const float2 xv = __half22float2(
                *reinterpret_cast<const __half2*>(x + (size_t)s * 64 + f0));
            const float we0 = wbuf[wv][0][ei];
            const float we1 = wbuf[wv][1][ei];
            const float we2 = wbuf[wv][2][ei];
            a00 += we0 * xv.x; a01 += we1 * xv.x; a02 += we2 * xv.x;
            a10 += we0 * xv.y; a11 += we1 * xv.y; a12 += we2 * xv.y;
        }
        if (e < cnt && p == 0) {
            const int s = cbuf[wv][e];
            const float2 xv = __half22float2(
                *reinterpret_cast<const __half2*>(x + (size_t)s * 64 + f0));
            const float we0 = wbuf[wv][0][e];
            const float we1 = wbuf[wv][1][e];
            const float we2 = wbuf[wv][2][e];
            a00 += we0 * xv.x; a01 += we1 * xv.x; a02 += we2 * xv.x;
            a10 += we0 * xv.y; a11 += we1 * xv.y; a12 += we2 * xv.y;
        }
    }
    a00 += __shfl_xor(a00, 32); a01 += __shfl_xor(a01, 32); a02 += __shfl_xor(a02, 32);
    a10 += __shfl_xor(a10, 32); a11 += __shfl_xor(a11, 32); a12 += __shfl_xor(a12, 32);
#pragma unroll
    for (int off = 32; off > 0; off >>= 1) {
        sw0 += __shfl_xor(sw0, off);
        sw1 += __shfl_xor(sw1, off);
        sw2 += __shfl_xor(sw2, off);
    }
    if (lane < 32) {
        __half* __restrict__ ao = agg + (size_t)n * 192;
        if (je > jb) {
            const float i0 = 1.f / sw0, i1 = 1.f / sw1, i2 = 1.f / sw2;
            *reinterpret_cast<__half2*>(ao + f0) = __floats2half2_rn(a00 * i0, a10 * i0);
            *reinterpret_cast<__half2*>(ao + 64 + f0) = __floats2half2_rn(a01 * i1, a11 * i1);
            *reinterpret_cast<__half2*>(ao + 128 + f0) = __floats2half2_rn(a02 * i2, a12 * i2);
        } else {
            const __half2 z = __floats2half2_rn(0.f, 0.f);
            *reinterpret_cast<__half2*>(ao + f0) = z;
            *reinterpret_cast<__half2*>(ao + 64 + f0) = z;
            *reinterpret_cast<__half2*>(ao + 128 + f0) = z;
        }
    }
}

// ---------------- Wa2/Wr2 precompute (float4-packed [64][4]) -----------------
__global__ void __launch_bounds__(192) k_prepA(const float* __restrict__ W2,
                                               const float* __restrict__ al2,
                                               const float* __restrict__ ar2,
                                               float* __restrict__ Wa2,
                                               float* __restrict__ Wr2) {
    const int t = threadIdx.x;
    const int h = t >> 6, k = t & 63;
    float sa = 0.f, sr = 0.f;
    for (int f = 0; f < 64; ++f) {
        const float w = W2[k * 192 + h * 64 + f];
        sa += w * al2[h * 64 + f];
        sr += w * ar2[h * 64 + f];
    }
    Wa2[k * 4 + h] = sa;
    Wr2[k * 4 + h] = sr;
    if (h == 0) { Wa2[k * 4 + 3] = 0.f; Wr2[k * 4 + 3] = 0.f; }
}

// ---------------- layer-1 post-agg GEMM + fused el2/er2 ----------------------
template <int KE, int AS, int HOFF>
__global__ void __launch_bounds__(192) k_gemm2(const float* __restrict__ agg,
                                               const float* __restrict__ W,
                                               const float* __restrict__ bias,
                                               const float* __restrict__ Wa2,
                                               const float* __restrict__ Wr2,
                                               __half* __restrict__ hout,
                                               float* __restrict__ el,
                                               float* __restrict__ er) {
    const int NPB = 16;
    const int h = threadIdx.x >> 6;
    const int c = threadIdx.x & 63;
    float wreg[KE];
#pragma unroll
    for (int k = 0; k < KE; ++k) wreg[k] = W[k * 192 + h * 64 + c];

    __shared__ float At[NPB * AS];
    __shared__ float part[3][NPB][64];
    const int nbase = blockIdx.x * NPB;         // 3125 * 16 = 50000 exact

    const float4* __restrict__ src4 =
        reinterpret_cast<const float4*>(agg + (size_t)nbase * AS);
    float4* At4 = reinterpret_cast<float4*>(At);
    for (int idx = threadIdx.x; idx < NPB * AS / 4; idx += 192) At4[idx] = src4[idx];
    __syncthreads();

#pragma unroll
    for (int i = 0; i < NPB; ++i) {
        const float* __restrict__ ar = At + i * AS + h * HOFF;
        float acc = 0.f;
#pragma unroll
        for (int k = 0; k < KE; ++k) acc += ar[k] * wreg[k];
        part[h][i][c] = acc;
    }
    __syncthreads();
    const int lane = threadIdx.x & 63;
    const float4 wa = *reinterpret_cast<const float4*>(Wa2 + lane * 4);
    const float4 wr = *reinterpret_cast<const float4*>(Wr2 + lane * 4);
    for (int idx = threadIdx.x; idx < NPB * 64; idx += 192) {
        const int i = idx >> 6, cc = idx & 63;  // cc == lane (192 % 64 == 0)
        const float v = part[0][i][cc] + part[1][i][cc] + part[2][i][cc]
                      + bias[cc] + bias[64 + cc] + bias[128 + cc];
        hout[(size_t)(nbase + i) * 64 + cc] = __float2half(v);
        float e0 = v * wa.x, e1 = v * wa.y, e2 = v * wa.z;
        float r0 = v * wr.x, r1 = v * wr.y, r2 = v * wr.z;
#pragma unroll
        for (int off = 32; off > 0; off >>= 1) {
            e0 += __shfl_xor(e0, off); e1 += __shfl_xor(e1, off); e2 += __shfl_xor(e2, off);
            r0 += __shfl_xor(r0, off); r1 += __shfl_xor(r1, off); r2 += __shfl_xor(r2, off);
        }
        if (lane == 0) {
            *reinterpret_cast<float4*>(el + (size_t)(nbase + i) * 4) = make_float4(e0, e1, e2, 0.f);
            *reinterpret_cast<float4*>(er + (size_t)(nbase + i) * 4) = make_float4(r0, r1, r2, 0.f);
        }
    }
}

// ---------------- W2 -> fp16 effective-transpose table Wt16[n][192] ----------
__global__ void __launch_bounds__(256) k_prepW(const float* __restrict__ W,
                                               __half* __restrict__ Wt16) {
    const int idx = blockIdx.x * 256 + threadIdx.x;
    if (idx >= 64 * 192) return;
    const int n = idx / 192, ke = idx % 192;
    Wt16[idx] = __float2half(W[(ke & 63) * 192 + (ke >> 6) * 64 + n]);
}

// ---------------- layer-2 GEMM via MFMA, fragment-direct ---------------------
__global__ void __launch_bounds__(256) k_gemm3m(const __half* __restrict__ agg,
                                                const __half* __restrict__ Wt,
                                                const float* __restrict__ bias,
                                                __half* __restrict__ hout) {
    const int wv = threadIdx.x >> 6;
    const int lane = threadIdx.x & 63;
    const int quad = lane >> 4;
    const int t16 = lane & 15;
    const int nwave = blockIdx.x * 64 + wv * 16;

    const int arow = min(nwave + t16, N_NODES - 1);
    half8 a[6];
#pragma unroll
    for (int kb = 0; kb < 6; ++kb)
        a[kb] = *reinterpret_cast<const half8*>(agg + (size_t)arow * 192 + kb * 32 + quad * 8);

    float bs[4];
#pragma unroll
    for (int nt = 0; nt < 4; ++nt) {
        const int c = nt * 16 + t16;
        bs[nt] = bias[c] + bias[64 + c] + bias[128 + c];
    }

#pragma unroll
    for (int nt = 0; nt < 4; ++nt) {
        const __half* __restrict__ bt = Wt + (size_t)(nt * 16 + t16) * 192 + quad * 8;
        f32x4 acc = {0.f, 0.f, 0.f, 0.f};
#pragma unroll
        for (int kb = 0; kb < 6; ++kb) {
            const half8 b = *reinterpret_cast<const half8*>(bt + kb * 32);
            acc = __builtin_amdgcn_mfma_f32_16x16x32_f16(a[kb], b, acc, 0, 0, 0);
        }
        const int c = nt * 16 + t16;
#pragma unroll
        for (int r = 0; r < 4; ++r) {
            const int node = nwave + quad * 4 + r;
            if (node < N_NODES)
                hout[(size_t)node * 64 + c] = __float2half(acc[r] + bs[nt]);
        }
    }
}

// ---------------- layer 3: packed feat3p[N][12]={el3[0..2],feat[0..5],pad} ---
__global__ void __launch_bounds__(256) k_feat3(const __half* __restrict__ x,
                                               const float* __restrict__ W3,
                                               const float* __restrict__ al3,
                                               const float* __restrict__ ar3,
                                               float* __restrict__ feat3p,
                                               float* __restrict__ er3) {
    __shared__ float Wl[64 * 6];
    __shared__ float Wal[64 * 3];
    __shared__ float Wrl[64 * 3];
    __shared__ float xl[32 * 68];
    const int t = threadIdx.x;
    const int n0 = blockIdx.x * 32;
    const int nvalid = min(32, N_NODES - n0);
    for (int idx = t; idx < 384; idx += 256) Wl[idx] = W3[idx];
    if (t < 192) {
        const int k = t & 63, h = t >> 6;
        Wal[k * 3 + h] = W3[k * 6 + h * 2] * al3[h * 2] + W3[k * 6 + h * 2 + 1] * al3[h * 2 + 1];
        Wrl[k * 3 + h] = W3[k * 6 + h * 2] * ar3[h * 2] + W3[k * 6 + h * 2 + 1] * ar3[h * 2 + 1];
    }
    for (int idx = t; idx < nvalid * 64; idx += 256)
        xl[(idx >> 6) * 68 + (idx & 63)] = __half2float(x[(size_t)n0 * 64 + idx]);
    __syncthreads();

    const int i = t >> 3;
    const int slot = t & 7;
    if (i < nvalid && slot < 6) {
        float acc = 0.f;
#pragma unroll
        for (int k4 = 0; k4 < 16; ++k4) {
            const float4 xv = *reinterpret_cast<const float4*>(&xl[i * 68 + 4 * k4]);
            acc += Wl[(4 * k4 + 0) * 6 + slot] * xv.x;
            acc += Wl[(4 * k4 + 1) * 6 + slot] * xv.y;
            acc += Wl[(4 * k4 + 2) * 6 + slot] * xv.z;
            acc += Wl[(4 * k4 + 3) * 6 + slot] * xv.w;
        }
        feat3p[(size_t)(n0 + i) * 12 + 3 + slot] = acc;   // feat at offsets 3..8
    }
    if (t < 192) {
        const int ii = t / 6, ss = t % 6;
        if (ii < nvalid) {
            const int hh = (ss < 3) ? ss : ss - 3;
            const float* __restrict__ wt = (ss < 3) ? Wal : Wrl;
            float acc = 0.f;
#pragma unroll 4
            for (int k = 0; k < 64; ++k) acc += xl[ii * 68 + k] * wt[k * 3 + hh];
            if (ss < 3) feat3p[(size_t)(n0 + ii) * 12 + hh] = acc;   // el3 at 0..2
            else        er3[(size_t)(n0 + ii) * 4 + hh] = acc;
        }
    }
}

// ---------------- layer-3 aggregation: wave/node, 8 edges/instruction --------
__global__ void __launch_bounds__(256) k_agg3(const float* __restrict__ feat3p,
                                              const float* __restrict__ er3,
                                              const float* __restrict__ b3,
                                              const int* __restrict__ rowp,
                                              const int* __restrict__ col,
                                              float* __restrict__ out) {
    const int wv = threadIdx.x >> 6;
    const int lane = threadIdx.x & 63;
    const int n = blockIdx.x * 4 + wv;          // grid exact: 12500*4
    const int jb = rowp[n], je = rowp[n + 1];

    __shared__ float wbuf[4][3][68];
    __shared__ int cbuf[4][68];
    __shared__ float comb[4][8];
    const float4 er4 = *reinterpret_cast<const float4*>(er3 + (size_t)n * 4);
    const int s8 = lane & 7;
    const int ep = lane >> 3;
    const int hh = (s8 < 6) ? (s8 >> 1) : 0;
    float acc = 0.f;
    float sw0 = 0.f, sw1 = 0.f, sw2 = 0.f;

    for (int c0 = jb; c0 < je; c0 += 64) {
        const int cnt = min(64, je - c0);
        float w0 = 0.f, w1 = 0.f, w2 = 0.f;
        if (lane < cnt) {
            const int s = col[c0 + lane];
            cbuf[wv][lane] = s;
            const float4 e4 = *reinterpret_cast<const float4*>(feat3p + (size_t)s * 12);
            w0 = __expf(lrelu(e4.x + er4.x));
            w1 = __expf(lrelu(e4.y + er4.y));
            w2 = __expf(lrelu(e4.z + er4.z));
            wbuf[wv][0][lane] = w0;
            wbuf[wv][1][lane] = w1;
            wbuf[wv][2][lane] = w2;
        }
        sw0 += w0; sw1 += w1; sw2 += w2;
        for (int e = ep; e < cnt; e += 8) {
            const int s = cbuf[wv][e];
            const float w = wbuf[wv][hh][e];
            const float f = feat3p[(size_t)s * 12 + 3 + s8];  // s8=6,7 read pad
            acc += w * f;
        }
    }
    acc += __shfl_xor(acc, 8);
    acc += __shfl_xor(acc, 16);
    acc += __shfl_xor(acc, 32);
#pragma unroll
    for (int off = 32; off > 0; off >>= 1) {
        sw0 += __shfl_xor(sw0, off);
        sw1 += __shfl_xor(sw1, off);
        sw2 += __shfl_xor(sw2, off);
    }
    if (ep == 0 && s8 < 6) {
        const float swh = (hh == 0) ? sw0 : (hh == 1 ? sw1 : sw2);
        comb[wv][s8] = (je > jb) ? acc / swh : 0.f;
    }
    if (lane < 2) {
        const float bc = b3[lane] + b3[lane + 2] + b3[lane + 4];
        out[(size_t)n * 2 + lane] = comb[wv][lane] + comb[wv][lane + 2] + comb[wv][lane + 4] + bc;
    }
}

extern "C" void kernel_launch(void* const* d_in, const int* in_sizes, int n_in,
                              void* d_out, int out_size, void* d_ws, size_t ws_size,
                              hipStream_t stream) {
    const float* feats = (const float*)d_in[0];
    const int* src = (const int*)d_in[1];
    const int* dst = (const int*)d_in[2];
    const float* W1 = (const float*)d_in[3];
    const float* al1 = (const float*)d_in[4];
    const float* ar1 = (const float*)d_in[5];
    const float* b1 = (const float*)d_in[6];
    const float* W2 = (const float*)d_in[7];
    const float* al2 = (const float*)d_in[8];
    const float* ar2 = (const float*)d_in[9];
    const float* b2 = (const float*)d_in[10];
    const float* W3 = (const float*)d_in[11];
    const float* al3 = (const float*)d_in[12];
    const float* ar3 = (const float*)d_in[13];
    const float* b3 = (const float*)d_in[14];
    float* out = (float*)d_out;

    char* ws = (char*)d_ws;
    size_t off = 0;
    auto alloc = [&](size_t bytes) {
        void* p = ws + off;
        off += (bytes + 255) & ~(size_t)255;
        return p;
    };
    float* agg = (float*)alloc((size_t)N_NODES * 28 * 4);        // L1 agg fp32 [N][28]
    __half* aggH = (__half*)alloc((size_t)N_NODES * 192 * 2);    // L2 agg fp16 [N][192]
    __half* hbufH = (__half*)alloc((size_t)N_NODES * 64 * 2);    // fp16 hidden
    float* xp = (float*)alloc((size_t)N_NODES * 12 * 4);         // packed x+el1
    float* el = (float*)alloc((size_t)N_NODES * 4 * 4);
    float* er = (float*)alloc((size_t)N_NODES * 4 * 4);
    int* bcnt = (int*)alloc(512 * 4);                            // bcnt[256] + bfill[256]
    int* bfill = bcnt + 256;
    int* bktbase = (int*)alloc(256 * 4);
    int* rowp = (int*)alloc((size_t)(N_NODES + 1) * 4);
    int* col = (int*)alloc((size_t)N_EDGES * 4);
    unsigned int* stage = (unsigned int*)alloc((size_t)N_EDGES * 4);
    __half* Wt16 = (__half*)alloc((size_t)64 * 192 * 2);         // 24 KB fp16 W2^T
    float* Wa2 = (float*)alloc(256 * 4);
    float* Wr2 = (float*)alloc(256 * 4);
    float* feat3p = (float*)alloc((size_t)N_NODES * 12 * 4);     // packed el3+feat3
    (void)ws_size;

    // ---- CSR build ----
    hipMemsetAsync(bcnt, 0, 512 * 4, stream);
    k_cntb<<<NB_BIN, 256, 0, stream>>>(dst, bcnt);
    k_scanb<<<1, 256, 0, stream>>>(bcnt, bktbase, rowp);
    k_bin<<<NB_BIN, 256, 0, stream>>>(src, dst, bktbase, bfill, stage);
    k_bscatter2<<<NBKT, 256, 0, stream>>>(stage, bktbase, rowp, col);
    k_prepW<<<48, 256, 0, stream>>>(W2, Wt16);
    k_prepA<<<1, 192, 0, stream>>>(W2, al2, ar2, Wa2, Wr2);

    const int ab = N_NODES / 4;             // wave/node kernels: 4 waves/block
    const int qb = N_NODES / 16;            // k_aggw9: 16 nodes/block (quarter-wave)
    const int gb2 = N_NODES / 16;           // k_gemm2: 16 nodes/block
    const int gbm = (N_NODES + 63) / 64;    // k_gemm3m: 64 nodes/block
    const int nb = (N_NODES + 255) / 256;
    const int nb3 = (N_NODES + 31) / 32;

    // ---- layer 1 (packed xp; lane-per-edge aggregation) ----
    k_el9p<<<nb, 256, 0, stream>>>(feats, W1, al1, ar1, xp, er);
    k_aggw9<<<qb, 256, 0, stream>>>(xp, er, rowp, col, agg);
    k_gemm2<9, 28, 9><<<gb2, 192, 0, stream>>>(agg, W1, b1, Wa2, Wr2, hbufH, el, er);

    // ---- layer 2 (el2/er2 from k_gemm2 epilogue) ----
    k_aggw64<<<ab, 256, 0, stream>>>(hbufH, el, er, rowp, col, aggH);
    k_gemm3m<<<gbm, 256, 0, stream>>>(aggH, Wt16, b2, hbufH);

    // ---- layer 3 (packed feat3p; er3 in er buffer) ----
    k_feat3<<<nb3, 256, 0, stream>>>(hbufH, W3, al3, ar3, feat3p, er);
    k_agg3<<<ab, 256, 0, stream>>>(feat3p, er, b3, rowp, col, out);
}